// Round 6
// baseline (260.966 us; speedup 1.0000x reference)
//
#include <hip/hip_runtime.h>

#define D 128
#define NB 256          // counting-sort chunks (one block each)
#define Q 8             // quarters for the b-dimension scan
#define BQ (NB / Q)     // blocks per quarter = 32
#define NBINS_MAX 10016 // max nodes supported by LDS histogram (~40 KB)
#define NPB 8           // nodes per aggemm block (one wave each)

// ---------------- fused per-chunk LDS histograms of dst and src ----------------
__global__ __launch_bounds__(256) void hist_kernel(const int* __restrict__ src, const int* __restrict__ dst,
                                                   int* __restrict__ pd, unsigned short* __restrict__ ps,
                                                   int E, int n) {
    __shared__ int hd[NBINS_MAX];
    __shared__ int hs[NBINS_MAX];
    int b = blockIdx.x, t = threadIdx.x;
    int chunk = (E + NB - 1) / NB;
    int e0 = b * chunk, e1 = min(e0 + chunk, E);
    for (int i = t; i < n; i += 256) { hd[i] = 0; hs[i] = 0; }
    __syncthreads();
    for (int e = e0 + t; e < e1; e += 256) {
        atomicAdd(&hd[dst[e]], 1);
        atomicAdd(&hs[src[e]], 1);
    }
    __syncthreads();
    for (int i = t; i < n; i += 256) {
        pd[(size_t)b * n + i] = hd[i];
        ps[(size_t)b * n + i] = (unsigned short)hs[i];
    }
}

// ---------------- within-quarter exclusive scan of pd along b (in place) ----------------
__global__ __launch_bounds__(256) void colscan_kernel(int* __restrict__ pd, const unsigned short* __restrict__ ps,
                                                      int* __restrict__ qtot_d, int* __restrict__ qtot_s, int n) {
    int bin = blockIdx.x * 256 + threadIdx.x;
    int q = blockIdx.y;
    if (bin >= n) return;
    int b0 = q * BQ;
    int run = 0, ssum = 0;
#pragma unroll 8
    for (int j = 0; j < BQ; ++j) {
        size_t idx = (size_t)(b0 + j) * n + bin;
        int v = pd[idx];
        pd[idx] = run;
        run += v;
        ssum += (int)ps[idx];
    }
    qtot_d[(size_t)q * n + bin] = run;
    qtot_s[(size_t)q * n + bin] = ssum;
}

// ---------------- per-bin: scan quarter totals -> bases; degrees -> norms ----------------
__global__ __launch_bounds__(256) void finalize_kernel(int* __restrict__ qtot_d /* becomes qbase */,
                                                       const int* __restrict__ qtot_s,
                                                       int* __restrict__ in_deg,
                                                       float* __restrict__ norm_src, float* __restrict__ norm_dst,
                                                       int n) {
    int bin = blockIdx.x * 256 + threadIdx.x;
    if (bin >= n) return;
    int run = 0;
#pragma unroll
    for (int q = 0; q < Q; ++q) {
        size_t i = (size_t)q * n + bin;
        int v = qtot_d[i];
        qtot_d[i] = run;
        run += v;
    }
    in_deg[bin] = run;
    norm_dst[bin] = rsqrtf(fmaxf((float)run, 1.0f));
    int tot = 0;
#pragma unroll
    for (int q = 0; q < Q; ++q) tot += qtot_s[(size_t)q * n + bin];
    norm_src[bin] = rsqrtf(fmaxf((float)tot, 1.0f));
}

// ---------------- exclusive scan of in_deg -> row_start (single block, LDS-staged) ----------------
__global__ __launch_bounds__(1024) void scan_kernel(const int* __restrict__ in_deg, int* __restrict__ row_start, int n) {
    __shared__ int buf[NBINS_MAX];
    __shared__ int part[1024];
    int t = threadIdx.x;
    for (int i = t; i < n; i += 1024) buf[i] = in_deg[i];
    __syncthreads();
    int ipt = (n + 1023) / 1024;
    int lo = min(t * ipt, n), hi = min(lo + ipt, n);
    int s = 0;
    for (int i = lo; i < hi; ++i) s += buf[i];
    part[t] = s;
    __syncthreads();
    for (int off = 1; off < 1024; off <<= 1) {
        int v = 0;
        if (t >= off) v = part[t - off];
        __syncthreads();
        if (t >= off) part[t] += v;
        __syncthreads();
    }
    int run = part[t] - s;
    for (int i = lo; i < hi; ++i) {
        int v = buf[i];
        buf[i] = run;
        run += v;
    }
    __syncthreads();
    for (int i = t; i < n; i += 1024) row_start[i] = buf[i];
    if (t == 0) row_start[n] = part[1023];
}

// ---------------- CSR fill: LDS cursor pre-seeded with absolute slot base ----------------
// Record weight = ew[e] * norm_src[src[e]]  (layer-invariant; folds the src-norm).
__global__ __launch_bounds__(256) void fill_kernel(const int* __restrict__ src, const int* __restrict__ dst,
                                                   const float* __restrict__ ew, const float* __restrict__ ns,
                                                   const int* __restrict__ row_start, const int* __restrict__ qbase,
                                                   const int* __restrict__ pd,
                                                   int2* __restrict__ sorted, int E, int n) {
    __shared__ int cursor[NBINS_MAX];
    int b = blockIdx.x, t = threadIdx.x;
    int q = b / BQ;
    int chunk = (E + NB - 1) / NB;
    int e0 = b * chunk, e1 = min(e0 + chunk, E);
    for (int i = t; i < n; i += 256)
        cursor[i] = row_start[i] + qbase[(size_t)q * n + i] + pd[(size_t)b * n + i];
    __syncthreads();
    for (int e = e0 + t; e < e1; e += 256) {
        int d = dst[e];
        int slot = atomicAdd(&cursor[d], 1);
        int s = src[e];
        int2 rec;
        rec.x = s;
        rec.y = __float_as_int(ew[e] * ns[s]);
        sorted[slot] = rec;
    }
}

// ---------------- fused aggregate + GEMM, one wave per node ----------------
// 512 threads = 8 waves = 8 nodes. Phase 1: wave w gathers node row0+w into
// registers (float2/lane, 8-edge unroll) -> sA row. Phase 2: 8x128 tile GEMM,
// thread = (row = tid&7, cols = (tid>>3)*2); W row-chunks shared 8-ways.
__global__ __launch_bounds__(512) void aggemm_kernel(const float* __restrict__ h, const int* __restrict__ row_start,
                                                     const int2* __restrict__ sorted, const float* __restrict__ W,
                                                     const float* __restrict__ bias, const float* __restrict__ norm_dst,
                                                     float* __restrict__ out, int n) {
    __shared__ float sA[NPB * 132];
    int tid = threadIdx.x;
    int wave = tid >> 6;
    int lane = tid & 63;
    int row0 = blockIdx.x * NPB;
    int node = row0 + wave;

    float ax = 0.f, ay = 0.f;
    if (node < n) {
        int beg = row_start[node];
        int end = row_start[node + 1];
        int s = beg;
        if (s < end && (s & 1)) {   // peel to even index -> 16B-aligned int4 record loads
            int2 rr = sorted[s];
            float c = __int_as_float(rr.y);
            float2 xv = *(const float2*)(h + (size_t)rr.x * D + lane * 2);
            ax = fmaf(c, xv.x, ax); ay = fmaf(c, xv.y, ay);
            ++s;
        }
        for (; s + 8 <= end; s += 8) {    // 8 independent 512B gathers in flight
            int4 p0 = *(const int4*)(sorted + s);
            int4 p1 = *(const int4*)(sorted + s + 2);
            int4 p2 = *(const int4*)(sorted + s + 4);
            int4 p3 = *(const int4*)(sorted + s + 6);
            float2 x0 = *(const float2*)(h + (size_t)p0.x * D + lane * 2);
            float2 x1 = *(const float2*)(h + (size_t)p0.z * D + lane * 2);
            float2 x2 = *(const float2*)(h + (size_t)p1.x * D + lane * 2);
            float2 x3 = *(const float2*)(h + (size_t)p1.z * D + lane * 2);
            float2 x4 = *(const float2*)(h + (size_t)p2.x * D + lane * 2);
            float2 x5 = *(const float2*)(h + (size_t)p2.z * D + lane * 2);
            float2 x6 = *(const float2*)(h + (size_t)p3.x * D + lane * 2);
            float2 x7 = *(const float2*)(h + (size_t)p3.z * D + lane * 2);
            float c0 = __int_as_float(p0.y), c1 = __int_as_float(p0.w);
            float c2 = __int_as_float(p1.y), c3 = __int_as_float(p1.w);
            float c4 = __int_as_float(p2.y), c5 = __int_as_float(p2.w);
            float c6 = __int_as_float(p3.y), c7 = __int_as_float(p3.w);
            ax = fmaf(c0, x0.x, ax); ay = fmaf(c0, x0.y, ay);
            ax = fmaf(c1, x1.x, ax); ay = fmaf(c1, x1.y, ay);
            ax = fmaf(c2, x2.x, ax); ay = fmaf(c2, x2.y, ay);
            ax = fmaf(c3, x3.x, ax); ay = fmaf(c3, x3.y, ay);
            ax = fmaf(c4, x4.x, ax); ay = fmaf(c4, x4.y, ay);
            ax = fmaf(c5, x5.x, ax); ay = fmaf(c5, x5.y, ay);
            ax = fmaf(c6, x6.x, ax); ay = fmaf(c6, x6.y, ay);
            ax = fmaf(c7, x7.x, ax); ay = fmaf(c7, x7.y, ay);
        }
        for (; s + 2 <= end; s += 2) {
            int4 p = *(const int4*)(sorted + s);
            float2 x0 = *(const float2*)(h + (size_t)p.x * D + lane * 2);
            float2 x1 = *(const float2*)(h + (size_t)p.z * D + lane * 2);
            float c0 = __int_as_float(p.y), c1 = __int_as_float(p.w);
            ax = fmaf(c0, x0.x, ax); ay = fmaf(c0, x0.y, ay);
            ax = fmaf(c1, x1.x, ax); ay = fmaf(c1, x1.y, ay);
        }
        if (s < end) {
            int2 rr = sorted[s];
            float c = __int_as_float(rr.y);
            float2 xv = *(const float2*)(h + (size_t)rr.x * D + lane * 2);
            ax = fmaf(c, xv.x, ax); ay = fmaf(c, xv.y, ay);
        }
    }
    *(float2*)(&sA[wave * 132 + lane * 2]) = make_float2(ax, ay);
    __syncthreads();

    // GEMM phase: out[r][c0..c0+1] = relu((sA[row]·W[:,c0..c0+1]) * nd + bias)
    int row = tid & (NPB - 1);
    int c0 = (tid >> 3) * 2;
    const float* sa = &sA[row * 132];
    float a0 = 0.f, a1 = 0.f;
#pragma unroll 8
    for (int k = 0; k < D; ++k) {
        float a = sa[k];
        float2 w = *(const float2*)(W + (size_t)k * D + c0);
        a0 = fmaf(a, w.x, a0);
        a1 = fmaf(a, w.y, a1);
    }
    int r = row0 + row;
    if (r < n) {
        float nd = norm_dst[r];
        float2 o;
        o.x = fmaxf(fmaf(a0, nd, bias[c0 + 0]), 0.f);
        o.y = fmaxf(fmaf(a1, nd, bias[c0 + 1]), 0.f);
        *(float2*)(out + (size_t)r * D + c0) = o;
    }
}

extern "C" void kernel_launch(void* const* d_in, const int* in_sizes, int n_in,
                              void* d_out, int out_size, void* d_ws, size_t ws_size,
                              hipStream_t stream) {
    const float* x  = (const float*)d_in[0];
    const float* ew = (const float*)d_in[1];
    const float* W0 = (const float*)d_in[2];
    const float* b0 = (const float*)d_in[3];
    const float* W1 = (const float*)d_in[4];
    const float* b1 = (const float*)d_in[5];
    const int* src  = (const int*)d_in[6];
    const int* dst  = (const int*)d_in[7];
    float* out = (float*)d_out;

    int n = in_sizes[0] / D;   // 10000
    int E = in_sizes[6];       // 640000
    if (n <= 0 || E <= 0) return;

    char* ws = (char*)d_ws;
    size_t off = 0;
    auto alloc = [&](size_t bytes) -> void* {
        void* p = ws + off;
        off = (off + bytes + 255) & ~(size_t)255;
        return p;
    };
    int* row_start  = (int*)alloc(((size_t)n + 1) * 4);
    int* in_deg     = (int*)alloc((size_t)n * 4);
    float* norm_src = (float*)alloc((size_t)n * 4);
    float* norm_dst = (float*)alloc((size_t)n * 4);
    int* qtot_d     = (int*)alloc((size_t)Q * n * 4);   // becomes qbase in finalize
    int* qtot_s     = (int*)alloc((size_t)Q * n * 4);
    size_t sorted_bytes = (size_t)E * 8;
    size_t ps_bytes = (size_t)NB * n * 2;
    int2* sorted    = (int2*)alloc(sorted_bytes > ps_bytes ? sorted_bytes : ps_bytes);
    float* B1       = (float*)alloc((size_t)n * D * 4);   // h1 (layer-1 output)
    float* B2       = (float*)alloc((size_t)n * D * 4);   // pd backing only
    (void)B2;
    // pd (NB*n ints = 10.24 MB) aliases B1+B2 (contiguous, both 256B-rounded);
    // consumed by fill_kernel before aggemm writes B1.
    int* pd = (int*)B1;
    // ps (NB*n ushorts) aliases sorted; consumed by colscan before fill writes sorted.
    unsigned short* ps = (unsigned short*)sorted;

    int nb = (n + 255) / 256;
    int gb = (n + NPB - 1) / NPB;   // 1250 blocks, one wave per node

    hist_kernel<<<NB, 256, 0, stream>>>(src, dst, pd, ps, E, n);
    colscan_kernel<<<dim3(nb, Q), 256, 0, stream>>>(pd, ps, qtot_d, qtot_s, n);
    finalize_kernel<<<nb, 256, 0, stream>>>(qtot_d, qtot_s, in_deg, norm_src, norm_dst, n);
    scan_kernel<<<1, 1024, 0, stream>>>(in_deg, row_start, n);
    fill_kernel<<<NB, 256, 0, stream>>>(src, dst, ew, norm_src, row_start, qtot_d, pd, sorted, E, n);

    // layer 1: aggregate x (norm_src folded in records) + GEMM -> B1
    aggemm_kernel<<<gb, 512, 0, stream>>>(x, row_start, sorted, W0, b0, norm_dst, B1, n);
    // layer 2: aggregate B1 + GEMM -> out
    aggemm_kernel<<<gb, 512, 0, stream>>>(B1, row_start, sorted, W1, b1, norm_dst, out, n);
}

// Round 7
// 231.763 us; speedup vs baseline: 1.1260x; 1.1260x over previous
//
#include <hip/hip_runtime.h>

#define D 128
#define NB 256          // counting-sort chunks (one block each)
#define Q 8             // quarters for the b-dimension scan
#define BQ (NB / Q)     // blocks per quarter = 32
#define NBINS_MAX 10016 // max nodes supported by LDS histogram (~40 KB)
#define TROWS 16

// ---------------- fused per-chunk LDS histograms of dst and src ----------------
__global__ __launch_bounds__(256) void hist_kernel(const int* __restrict__ src, const int* __restrict__ dst,
                                                   int* __restrict__ pd, unsigned short* __restrict__ ps,
                                                   int E, int n) {
    __shared__ int hd[NBINS_MAX];
    __shared__ int hs[NBINS_MAX];
    int b = blockIdx.x, t = threadIdx.x;
    int chunk = (E + NB - 1) / NB;
    int e0 = b * chunk, e1 = min(e0 + chunk, E);
    for (int i = t; i < n; i += 256) { hd[i] = 0; hs[i] = 0; }
    __syncthreads();
    for (int e = e0 + t; e < e1; e += 256) {
        atomicAdd(&hd[dst[e]], 1);
        atomicAdd(&hs[src[e]], 1);
    }
    __syncthreads();
    for (int i = t; i < n; i += 256) {
        pd[(size_t)b * n + i] = hd[i];
        ps[(size_t)b * n + i] = (unsigned short)hs[i];
    }
}

// ---------------- within-quarter exclusive scan of pd along b (in place) ----------------
__global__ __launch_bounds__(256) void colscan_kernel(int* __restrict__ pd, const unsigned short* __restrict__ ps,
                                                      int* __restrict__ qtot_d, int* __restrict__ qtot_s, int n) {
    int bin = blockIdx.x * 256 + threadIdx.x;
    int q = blockIdx.y;
    if (bin >= n) return;
    int b0 = q * BQ;
    int run = 0, ssum = 0;
#pragma unroll 8
    for (int j = 0; j < BQ; ++j) {
        size_t idx = (size_t)(b0 + j) * n + bin;
        int v = pd[idx];
        pd[idx] = run;
        run += v;
        ssum += (int)ps[idx];
    }
    qtot_d[(size_t)q * n + bin] = run;
    qtot_s[(size_t)q * n + bin] = ssum;
}

// ---------------- per-bin: scan quarter totals -> bases; degrees -> norms ----------------
__global__ __launch_bounds__(256) void finalize_kernel(int* __restrict__ qtot_d /* becomes qbase */,
                                                       const int* __restrict__ qtot_s,
                                                       int* __restrict__ in_deg,
                                                       float* __restrict__ norm_src, float* __restrict__ norm_dst,
                                                       int n) {
    int bin = blockIdx.x * 256 + threadIdx.x;
    if (bin >= n) return;
    int run = 0;
#pragma unroll
    for (int q = 0; q < Q; ++q) {
        size_t i = (size_t)q * n + bin;
        int v = qtot_d[i];
        qtot_d[i] = run;
        run += v;
    }
    in_deg[bin] = run;
    norm_dst[bin] = rsqrtf(fmaxf((float)run, 1.0f));
    int tot = 0;
#pragma unroll
    for (int q = 0; q < Q; ++q) tot += qtot_s[(size_t)q * n + bin];
    norm_src[bin] = rsqrtf(fmaxf((float)tot, 1.0f));
}

// ---------------- exclusive scan of in_deg -> row_start (single block, LDS-staged) ----------------
__global__ __launch_bounds__(1024) void scan_kernel(const int* __restrict__ in_deg, int* __restrict__ row_start, int n) {
    __shared__ int buf[NBINS_MAX];
    __shared__ int part[1024];
    int t = threadIdx.x;
    for (int i = t; i < n; i += 1024) buf[i] = in_deg[i];
    __syncthreads();
    int ipt = (n + 1023) / 1024;
    int lo = min(t * ipt, n), hi = min(lo + ipt, n);
    int s = 0;
    for (int i = lo; i < hi; ++i) s += buf[i];
    part[t] = s;
    __syncthreads();
    for (int off = 1; off < 1024; off <<= 1) {
        int v = 0;
        if (t >= off) v = part[t - off];
        __syncthreads();
        if (t >= off) part[t] += v;
        __syncthreads();
    }
    int run = part[t] - s;
    for (int i = lo; i < hi; ++i) {
        int v = buf[i];
        buf[i] = run;
        run += v;
    }
    __syncthreads();
    for (int i = t; i < n; i += 1024) row_start[i] = buf[i];
    if (t == 0) row_start[n] = part[1023];
}

// ---------------- CSR fill: LDS cursor pre-seeded with absolute slot base ----------------
// Record weight = ew[e] * norm_src[src[e]]  (layer-invariant; folds the src-norm).
__global__ __launch_bounds__(256) void fill_kernel(const int* __restrict__ src, const int* __restrict__ dst,
                                                   const float* __restrict__ ew, const float* __restrict__ ns,
                                                   const int* __restrict__ row_start, const int* __restrict__ qbase,
                                                   const int* __restrict__ pd,
                                                   int2* __restrict__ sorted, int E, int n) {
    __shared__ int cursor[NBINS_MAX];
    int b = blockIdx.x, t = threadIdx.x;
    int q = b / BQ;
    int chunk = (E + NB - 1) / NB;
    int e0 = b * chunk, e1 = min(e0 + chunk, E);
    for (int i = t; i < n; i += 256)
        cursor[i] = row_start[i] + qbase[(size_t)q * n + i] + pd[(size_t)b * n + i];
    __syncthreads();
    for (int e = e0 + t; e < e1; e += 256) {
        int d = dst[e];
        int slot = atomicAdd(&cursor[d], 1);
        int s = src[e];
        int2 rec;
        rec.x = s;
        rec.y = __float_as_int(ew[e] * ns[s]);
        sorted[slot] = rec;
    }
}

// ---------------- XCD-partitioned aggregation ----------------
// blockIdx%8 -> XCD slot (round-robin dispatch heuristic). Slots 0-3 handle
// feature chunk [0,64), slots 4-7 chunk [64,128); each slot owns one node
// quad. Per-XCD hot x-slice = n*64*4B/... = 2.56MB -> L2-resident.
// One wave per (node, chunk): lane loads 1 float (256B/row-gather).
__global__ __launch_bounds__(256) void agg_kernel(const float* __restrict__ h, const int* __restrict__ row_start,
                                                  const int2* __restrict__ sorted, float* __restrict__ out,
                                                  int n, int qn) {
    int slot  = blockIdx.x & 7;
    int g     = blockIdx.x >> 3;
    int chunk = slot >> 2;         // 0 or 1
    int quad  = slot & 3;          // node quad
    int wave  = threadIdx.x >> 6;
    int lane  = threadIdx.x & 63;
    int node  = quad * qn + g * 4 + wave;
    int hiN   = min((quad + 1) * qn, n);
    if (node >= hiN) return;
    const float* hc = h + chunk * 64 + lane;
    int beg = row_start[node];
    int end = row_start[node + 1];
    float acc = 0.f;
    int s = beg;
    if (s < end && (s & 1)) {   // peel to even index -> 16B-aligned int4 record loads
        int2 rr = sorted[s];
        acc = fmaf(__int_as_float(rr.y), hc[rr.x << 7], acc);
        ++s;
    }
    for (; s + 8 <= end; s += 8) {    // 8 independent 256B gathers in flight
        int4 p0 = *(const int4*)(sorted + s);
        int4 p1 = *(const int4*)(sorted + s + 2);
        int4 p2 = *(const int4*)(sorted + s + 4);
        int4 p3 = *(const int4*)(sorted + s + 6);
        float x0 = hc[p0.x << 7];
        float x1 = hc[p0.z << 7];
        float x2 = hc[p1.x << 7];
        float x3 = hc[p1.z << 7];
        float x4 = hc[p2.x << 7];
        float x5 = hc[p2.z << 7];
        float x6 = hc[p3.x << 7];
        float x7 = hc[p3.z << 7];
        acc = fmaf(__int_as_float(p0.y), x0, acc);
        acc = fmaf(__int_as_float(p0.w), x1, acc);
        acc = fmaf(__int_as_float(p1.y), x2, acc);
        acc = fmaf(__int_as_float(p1.w), x3, acc);
        acc = fmaf(__int_as_float(p2.y), x4, acc);
        acc = fmaf(__int_as_float(p2.w), x5, acc);
        acc = fmaf(__int_as_float(p3.y), x6, acc);
        acc = fmaf(__int_as_float(p3.w), x7, acc);
    }
    for (; s + 2 <= end; s += 2) {
        int4 p = *(const int4*)(sorted + s);
        acc = fmaf(__int_as_float(p.y), hc[p.x << 7], acc);
        acc = fmaf(__int_as_float(p.w), hc[p.z << 7], acc);
    }
    if (s < end) {
        int2 rr = sorted[s];
        acc = fmaf(__int_as_float(rr.y), hc[rr.x << 7], acc);
    }
    out[((size_t)node << 7) + chunk * 64 + lane] = acc;
}

// ---------------- GEMM + epilogue: out = relu((A@W)*norm_dst[:,None] + b) ----------------
__global__ __launch_bounds__(256) void gemm_kernel(const float* __restrict__ A, const float* __restrict__ W,
                                                   const float* __restrict__ bias, const float* __restrict__ norm_dst,
                                                   float* __restrict__ out, int n) {
    __shared__ float sA[TROWS * 132];
    int tid = threadIdx.x;
    int row0 = blockIdx.x * TROWS;
    for (int i = tid; i < TROWS * 32; i += 256) {
        int r = i >> 5;
        int q = i & 31;
        int rr = row0 + r;
        float4 v = make_float4(0.f, 0.f, 0.f, 0.f);
        if (rr < n) v = *(const float4*)(A + (size_t)rr * D + q * 4);
        *(float4*)(&sA[r * 132 + q * 4]) = v;
    }
    __syncthreads();
    int ty = tid >> 4;
    int tx = tid & 15;
    int c0 = tx * 8;
    float acc[8];
#pragma unroll
    for (int j = 0; j < 8; ++j) acc[j] = 0.f;
    const float* sa = &sA[ty * 132];
#pragma unroll 4
    for (int k = 0; k < D; ++k) {
        float a = sa[k];
        float4 w0 = *(const float4*)(W + k * D + c0);
        float4 w1 = *(const float4*)(W + k * D + c0 + 4);
        acc[0] = fmaf(a, w0.x, acc[0]);
        acc[1] = fmaf(a, w0.y, acc[1]);
        acc[2] = fmaf(a, w0.z, acc[2]);
        acc[3] = fmaf(a, w0.w, acc[3]);
        acc[4] = fmaf(a, w1.x, acc[4]);
        acc[5] = fmaf(a, w1.y, acc[5]);
        acc[6] = fmaf(a, w1.z, acc[6]);
        acc[7] = fmaf(a, w1.w, acc[7]);
    }
    int r = row0 + ty;
    if (r < n) {
        float nd = norm_dst[r];
        float4 o0, o1;
        o0.x = fmaxf(fmaf(acc[0], nd, bias[c0 + 0]), 0.f);
        o0.y = fmaxf(fmaf(acc[1], nd, bias[c0 + 1]), 0.f);
        o0.z = fmaxf(fmaf(acc[2], nd, bias[c0 + 2]), 0.f);
        o0.w = fmaxf(fmaf(acc[3], nd, bias[c0 + 3]), 0.f);
        o1.x = fmaxf(fmaf(acc[4], nd, bias[c0 + 4]), 0.f);
        o1.y = fmaxf(fmaf(acc[5], nd, bias[c0 + 5]), 0.f);
        o1.z = fmaxf(fmaf(acc[6], nd, bias[c0 + 6]), 0.f);
        o1.w = fmaxf(fmaf(acc[7], nd, bias[c0 + 7]), 0.f);
        *(float4*)(out + (size_t)r * D + c0) = o0;
        *(float4*)(out + (size_t)r * D + c0 + 4) = o1;
    }
}

extern "C" void kernel_launch(void* const* d_in, const int* in_sizes, int n_in,
                              void* d_out, int out_size, void* d_ws, size_t ws_size,
                              hipStream_t stream) {
    const float* x  = (const float*)d_in[0];
    const float* ew = (const float*)d_in[1];
    const float* W0 = (const float*)d_in[2];
    const float* b0 = (const float*)d_in[3];
    const float* W1 = (const float*)d_in[4];
    const float* b1 = (const float*)d_in[5];
    const int* src  = (const int*)d_in[6];
    const int* dst  = (const int*)d_in[7];
    float* out = (float*)d_out;

    int n = in_sizes[0] / D;   // 10000
    int E = in_sizes[6];       // 640000
    if (n <= 0 || E <= 0) return;

    char* ws = (char*)d_ws;
    size_t off = 0;
    auto alloc = [&](size_t bytes) -> void* {
        void* p = ws + off;
        off = (off + bytes + 255) & ~(size_t)255;
        return p;
    };
    int* row_start  = (int*)alloc(((size_t)n + 1) * 4);
    int* in_deg     = (int*)alloc((size_t)n * 4);
    float* norm_src = (float*)alloc((size_t)n * 4);
    float* norm_dst = (float*)alloc((size_t)n * 4);
    int* qtot_d     = (int*)alloc((size_t)Q * n * 4);   // becomes qbase in finalize
    int* qtot_s     = (int*)alloc((size_t)Q * n * 4);
    size_t sorted_bytes = (size_t)E * 8;
    size_t ps_bytes = (size_t)NB * n * 2;
    int2* sorted    = (int2*)alloc(sorted_bytes > ps_bytes ? sorted_bytes : ps_bytes);
    float* B1       = (float*)alloc((size_t)n * D * 4);   // agg output
    float* B2       = (float*)alloc((size_t)n * D * 4);   // h1
    // pd (NB*n ints = 10.24 MB) aliases B1+B2 (contiguous, both 256B-rounded);
    // consumed by fill_kernel before agg writes B1.
    int* pd = (int*)B1;
    // ps (NB*n ushorts) aliases sorted; consumed by colscan before fill writes sorted.
    unsigned short* ps = (unsigned short*)sorted;

    int nb = (n + 255) / 256;
    int qn = (n + 3) / 4;                  // nodes per quad
    int ab = 8 * ((qn + 3) / 4);           // 8 XCD slots x groups of 4 nodes
    int gb = (n + TROWS - 1) / TROWS;

    hist_kernel<<<NB, 256, 0, stream>>>(src, dst, pd, ps, E, n);
    colscan_kernel<<<dim3(nb, Q), 256, 0, stream>>>(pd, ps, qtot_d, qtot_s, n);
    finalize_kernel<<<nb, 256, 0, stream>>>(qtot_d, qtot_s, in_deg, norm_src, norm_dst, n);
    scan_kernel<<<1, 1024, 0, stream>>>(in_deg, row_start, n);
    fill_kernel<<<NB, 256, 0, stream>>>(src, dst, ew, norm_src, row_start, qtot_d, pd, sorted, E, n);

    // layer 1: agg x (norm_src folded in records) -> B1, gemm -> B2
    agg_kernel<<<ab, 256, 0, stream>>>(x, row_start, sorted, B1, n, qn);
    gemm_kernel<<<gb, 256, 0, stream>>>(B1, W0, b0, norm_dst, B2, n);
    // layer 2: agg B2 -> B1, gemm -> out
    agg_kernel<<<ab, 256, 0, stream>>>(B2, row_start, sorted, B1, n, qn);
    gemm_kernel<<<gb, 256, 0, stream>>>(B1, W1, b1, norm_dst, out, n);
}